// Round 8
// baseline (796.642 us; speedup 1.0000x reference)
//
#include <hip/hip_runtime.h>
#include <hip/hip_bf16.h>

#define BB 4
#define NN 2048
#define DD 1024
#define HH 16
#define DHH 64
#define HB (HH*BB)   // 64

typedef __bf16 bf16;
typedef __bf16 bf16x4v __attribute__((ext_vector_type(4)));
typedef __bf16 bf16x8 __attribute__((ext_vector_type(8)));
typedef float f32x4 __attribute__((ext_vector_type(4)));
typedef float f32x16 __attribute__((ext_vector_type(16)));
typedef unsigned u32x2 __attribute__((ext_vector_type(2)));

#if __has_builtin(__builtin_amdgcn_permlane32_swap)
#define HAVE_PLSWAP 1
#else
#define HAVE_PLSWAP 0
#endif

// Q pre-scale: (1/sqrt(64)) * log2(e) so softmax runs in exp2 domain
#define QSCALE 0.18033688011112042f

__device__ __forceinline__ void async16(const void* g, void* l) {
    __builtin_amdgcn_global_load_lds(
        (const __attribute__((address_space(1))) unsigned int*)g,
        (__attribute__((address_space(3))) unsigned int*)l, 16, 0, 0);
}

__device__ __forceinline__ unsigned pkbf(float a, float b) {
    union { bf16 h[2]; unsigned u; } x;
    x.h[0] = (bf16)a; x.h[1] = (bf16)b;
    return x.u;
}

// ---------------- Fused PE-add + W-transpose (one launch) ----------------
// blocks [0, 8192): pe_add; blocks [8192, 11264): wtrans (3 x 32 x 32 tiles).
__global__ void pe_wtrans_kernel(const float* __restrict__ data,
                                 const float* __restrict__ Wq, const float* __restrict__ Wk,
                                 const float* __restrict__ Wv,
                                 bf16* __restrict__ xb, bf16* __restrict__ Bw) {
    __shared__ float s[32][33];
    int b = blockIdx.x;
    int tid = threadIdx.x;
    if (b < 8192) {
        int t = b * 256 + tid;
        int base = t * 4;
        int row = base >> 10;
        int d0 = base & 1023;
        int n = row & (NN - 1);
        const float LOG2_10000 = 13.287712379549449f;
        int pn = n & ~1;
        float denom_p = __builtin_amdgcn_exp2f((2.0f * (float)pn / (float)NN) * LOG2_10000);
        bool even_p = (n & 1) == 0;
        float4 dv = *(const float4*)(data + base);
        float din[4] = {dv.x, dv.y, dv.z, dv.w};
        bf16x4v ov;
        #pragma unroll
        for (int u = 0; u < 4; ++u) {
            int d = d0 + u;
            int di = d & ~1;
            float denom_i = __builtin_amdgcn_exp2f((2.0f * (float)di / (float)DD) * LOG2_10000);
            float a = (float)n / denom_i;
            float basev = ((d & 1) == 0) ? __sinf(a) : __cosf(a);
            float bm = (float)d / denom_p;
            float mult = even_p ? __sinf(bm) : __cosf(bm);
            ov[u] = (bf16)(din[u] + basev * mult);
        }
        *(bf16x4v*)(xb + base) = ov;
    } else {
        int bb = b - 8192;
        int bz = bb >> 10;            // 0..2
        int rem = bb & 1023;
        int by = (rem >> 5) * 32;     // k0
        int bx = (rem & 31) * 32;     // n0
        const float* W = (bz == 0) ? Wq : (bz == 1) ? Wk : Wv;
        bf16* Wt = Bw + (size_t)bz * 1024 * 1024;
        int tx = tid & 31, ty = tid >> 5;   // (32,8)
        #pragma unroll
        for (int i = 0; i < 32; i += 8)
            s[ty + i][tx] = W[(by + ty + i) * DD + bx + tx];
        __syncthreads();
        #pragma unroll
        for (int i = 0; i < 32; i += 8)
            Wt[(size_t)(bx + ty + i) * DD + by + tx] = (bf16)s[tx][ty + i];
    }
}

// ---------------- Fused QKV GEMM (32x32x16, dbuf) ----------------
// K and V outputs are emitted in ATTENTION FRAGMENT ORDER so the attention kernel can do
// fully-coalesced per-wave global loads with no LDS staging and no barriers:
//   Kf[hb][tile(32)][kh(2)][c(4)][lane(64)][8 bf16]   (8KB per tile image)
//   Vf[hb][tile(32)][kh(2)][kc(2)][d(2)][lane(64)][8] (8KB per tile image)
// lane = hi*32 + l32; Kf element = K[n = tile*64+kh*32+l32][dh = c*16+hi*8+e];
// Vf element = V^T[dh = d*32+l32][key = tile*64+(kh*4+kc*2+hi)*8+e].
__launch_bounds__(256)
__global__ void gemm_qkv_fused(const bf16* __restrict__ A,   // [8192][1024]
                               const bf16* __restrict__ Bw,  // [3072][1024]
                               const float* __restrict__ bq, const float* __restrict__ bk,
                               const float* __restrict__ bv,
                               bf16* __restrict__ Qs, bf16* __restrict__ Kf,
                               bf16* __restrict__ Vf) {
    __shared__ char smem[36864];   // staging: 2 x 16KB ; V epilogue: 128x130 bf16 = 33280B
    int tid = threadIdx.x;
    int w = tid >> 6, lane = tid & 63, l32 = lane & 31, hi = lane >> 5;
    int bi = blockIdx.x;
    int bn = bi >> 6;
    int bm = (bi & 7) * 8 + ((bi >> 3) & 7);   // XCD-clustered A-row tiles
    int m0 = bm * 128, n0 = bn * 128;
    int wm = (w & 1) * 64, wn = (w >> 1) * 64;

    int srow = tid >> 2;
    int g4 = (tid & 3) ^ (srow & 3);           // XOR-4 swizzle
    const bf16* aS0 = A + (size_t)(m0 + srow) * DD + g4 * 8;
    const bf16* aS1 = aS0 + (size_t)64 * DD;
    const bf16* bS0 = Bw + (size_t)(n0 + srow) * DD + g4 * 8;
    const bf16* bS1 = bS0 + (size_t)64 * DD;

    f32x16 acc[2][2];
    #pragma unroll
    for (int i = 0; i < 2; ++i)
        #pragma unroll
        for (int j = 0; j < 2; ++j)
            #pragma unroll
            for (int r = 0; r < 16; ++r) acc[i][j][r] = 0.f;

    async16(aS0, smem + w * 1024);
    async16(aS1, smem + 4096 + w * 1024);
    async16(bS0, smem + 8192 + w * 1024);
    async16(bS1, smem + 12288 + w * 1024);
    __syncthreads();

    for (int kk = 0; kk < DD; kk += 32) {
        char* buf  = smem + ((kk >> 5) & 1) * 16384;
        char* nbuf = smem + (((kk >> 5) & 1) ^ 1) * 16384;
        if (kk + 32 < DD) {
            async16(aS0 + kk + 32, nbuf + w * 1024);
            async16(aS1 + kk + 32, nbuf + 4096 + w * 1024);
            async16(bS0 + kk + 32, nbuf + 8192 + w * 1024);
            async16(bS1 + kk + 32, nbuf + 12288 + w * 1024);
        }
        const char* As = buf;
        const char* Bs = buf + 8192;
        bf16x8 af[2][2], bfr[2][2];
        #pragma unroll
        for (int mt = 0; mt < 2; ++mt) {
            int row = wm + mt * 32 + l32;
            #pragma unroll
            for (int kc = 0; kc < 2; ++kc)
                af[mt][kc] = *(const bf16x8*)(As + row * 64 + ((kc * 2 + hi) ^ (l32 & 3)) * 16);
        }
        #pragma unroll
        for (int nt = 0; nt < 2; ++nt) {
            int row = wn + nt * 32 + l32;
            #pragma unroll
            for (int kc = 0; kc < 2; ++kc)
                bfr[nt][kc] = *(const bf16x8*)(Bs + row * 64 + ((kc * 2 + hi) ^ (l32 & 3)) * 16);
        }
        #pragma unroll
        for (int mt = 0; mt < 2; ++mt)
            #pragma unroll
            for (int nt = 0; nt < 2; ++nt)
                #pragma unroll
                for (int kc = 0; kc < 2; ++kc)
                    acc[mt][nt] = __builtin_amdgcn_mfma_f32_32x32x16_bf16(
                        af[mt][kc], bfr[nt][kc], acc[mt][nt], 0, 0, 0);
        __syncthreads();
    }

    int mat = n0 >> 10;  // uniform per block (bn<8: Q, <16: K, else V)
    if (mat == 0) {
        #pragma unroll
        for (int nt = 0; nt < 2; ++nt) {
            int ncol = (n0 + wn + nt * 32 + l32) & 1023;
            float bias = bq[ncol];
            int h = ncol >> 6, dh = ncol & 63;
            #pragma unroll
            for (int mt = 0; mt < 2; ++mt) {
                int rowbase = m0 + wm + mt * 32 + 4 * hi;
                #pragma unroll
                for (int m4 = 0; m4 < 4; ++m4) {
                    #pragma unroll
                    for (int rr = 0; rr < 4; ++rr) {
                        int mrow = rowbase + 8 * m4 + rr;
                        int b_ = mrow >> 11, nn_ = mrow & 2047;
                        int hbi = h * BB + b_;
                        float v = acc[mt][nt][m4 * 4 + rr] + bias;
                        Qs[((size_t)hbi * NN + nn_) * DHH + dh] = (bf16)(v * QSCALE);
                    }
                }
            }
        }
    } else if (mat == 1) {
        // ---- K: scalar stores into fragment-order Kf ----
        #pragma unroll
        for (int nt = 0; nt < 2; ++nt) {
            int ncol = (n0 + wn + nt * 32 + l32) & 1023;
            float bias = bk[ncol];
            int h = ncol >> 6, dh = ncol & 63;
            int c = dh >> 4, hi2 = (dh >> 3) & 1, e = dh & 7;
            #pragma unroll
            for (int mt = 0; mt < 2; ++mt) {
                int rowbase = m0 + wm + mt * 32 + 4 * hi;
                #pragma unroll
                for (int m4 = 0; m4 < 4; ++m4) {
                    #pragma unroll
                    for (int rr = 0; rr < 4; ++rr) {
                        int mrow = rowbase + 8 * m4 + rr;
                        int b_ = mrow >> 11, nn_ = mrow & 2047;
                        int hbi = h * BB + b_;
                        int T = nn_ >> 6, r = nn_ & 63;
                        int khk = r >> 5, l32k = r & 31;
                        float v = acc[mt][nt][m4 * 4 + rr] + bias;
                        Kf[((size_t)(hbi * 32 + T)) * 4096 + khk * 2048 + c * 512 +
                           (hi2 * 32 + l32k) * 8 + e] = (bf16)v;
                    }
                }
            }
        }
    } else {
        // ---- V: bounce through LDS, then lane-contiguous 16B stores into Vf ----
        bf16* vl = (bf16*)smem;
        #pragma unroll
        for (int nt = 0; nt < 2; ++nt) {
            int ncol_l = wn + nt * 32 + l32;
            float bias = bv[(n0 + ncol_l) & 1023];
            #pragma unroll
            for (int mt = 0; mt < 2; ++mt) {
                int m_base = wm + mt * 32 + 4 * hi;
                #pragma unroll
                for (int m4 = 0; m4 < 4; ++m4) {
                    bf16x4v q;
                    #pragma unroll
                    for (int rr = 0; rr < 4; ++rr)
                        q[rr] = (bf16)(acc[mt][nt][m4 * 4 + rr] + bias);
                    *(bf16x4v*)(vl + ncol_l * 130 + m_base + 8 * m4) = q;
                }
            }
        }
        __syncthreads();
        int b_ = m0 >> 11;
        int tile0 = (m0 & 2047) >> 6;
        int h0 = (n0 & 1023) >> 6;
        // 2048 16B-units: [hh(2)][tt(2)][u(512)], u = kh*256 + kc*128 + d*64 + lane
        #pragma unroll
        for (int j = 0; j < 8; ++j) {
            int g = tid + 256 * j;
            int hh = g >> 10, tt = (g >> 9) & 1, u = g & 511;
            int khv = u >> 8, kcv = (u >> 7) & 1, dv = (u >> 6) & 1, lanev = u & 63;
            int hiv = lanev >> 5, l32v = lanev & 31;
            int col = hh * 64 + dv * 32 + l32v;
            int chunk = khv * 4 + kcv * 2 + hiv;
            bf16x8 vv = *(const bf16x8*)(vl + col * 130 + tt * 64 + chunk * 8);
            int hb2 = (h0 + hh) * BB + b_;
            *(bf16x8*)(Vf + ((size_t)(hb2 * 32 + tile0 + tt)) * 4096 + (size_t)u * 8) = vv;
        }
    }
}

// ---------------- Flash attention: barrier-free, fragment-order global loads ----------------
// K/V are pre-arranged by the GEMM in per-wave fragment order, so each fragment load is
// base + lane*16 -- one coalesced 1KB global_load_dwordx4, L2-resident (per-XCD working set
// = 8 hb x (256KB Kf + 256KB Vf) = 4MB = one L2; all readers of a line are co-XCD by the
// block swizzle). No LDS staging, no main-loop barriers, no vmcnt coupling, no bank
// conflicts; waves drift freely (kills the phase-lockstep that pinned MfmaUtil~30/VALU~47).
// Latency cover per wave: V issued before QK+softmax (~260cy); next-K issued after QK,
// consumed after softmax+PV (~300cy); both > L2 hit (~200cy).
__launch_bounds__(256, 4)
__global__ void attn_kernel(const bf16* __restrict__ Qs,   // [hb][n][dh], pre-scaled
                            const bf16* __restrict__ Kf,   // fragment order
                            const bf16* __restrict__ Vf,   // fragment order
                            float* __restrict__ out) {     // [hb][n][dh]
    __shared__ char smem[33280];   // epilogue only: O 32KB + Ls 512B
    int tid = threadIdx.x;
    int w = tid >> 6, lane = tid & 63, l32 = lane & 31, hi = lane >> 5;
    int qh = w & 1, kh = w >> 1;
    int bi = blockIdx.x;
    int xcd = bi & 7, jj = bi >> 3;
    int hb = xcd * 8 + (jj & 7);
    int qb = jj >> 3;
    int q0 = qb * 128;

    // Q B-frags for 2 q-sets: cols q0 + qh*64 + qs*32 + l32, k = dh c*16 + hi*8 + j
    bf16x8 qf[2][4];
    #pragma unroll
    for (int qs = 0; qs < 2; ++qs) {
        const bf16* qbase = Qs + ((size_t)hb * NN + q0 + qh * 64 + qs * 32 + l32) * DHH + hi * 8;
        #pragma unroll
        for (int c = 0; c < 4; ++c)
            qf[qs][c] = *(const bf16x8*)(qbase + c * 16);
    }

    // fragment-order bases: per tile stride 4096 bf16 (8KB)
    const bf16* kb = Kf + (size_t)hb * 32 * 4096 + kh * 2048 + lane * 8;
    const bf16* vb = Vf + (size_t)hb * 32 * 4096 + kh * 2048 + lane * 8;

    f32x16 o[2][2];   // [qs][d] partial over this wave's keys
    #pragma unroll
    for (int qs = 0; qs < 2; ++qs)
        #pragma unroll
        for (int d = 0; d < 2; ++d)
            #pragma unroll
            for (int r = 0; r < 16; ++r) o[qs][d][r] = 0.f;
    float ts[2] = {0.f, 0.f};

    // K frags for tile 0
    bf16x8 kf[4];
    #pragma unroll
    for (int c = 0; c < 4; ++c)
        kf[c] = *(const bf16x8*)(kb + c * 512);

    for (int kt = 0; kt < NN; kt += 64) {
        int tb = (kt >> 6) * 4096;

        // ---- V frags: issue early, consumed after QK+softmax ----
        bf16x8 vfr[2][2];
        #pragma unroll
        for (int kc = 0; kc < 2; ++kc)
            #pragma unroll
            for (int d = 0; d < 2; ++d)
                vfr[kc][d] = *(const bf16x8*)(vb + tb + kc * 1024 + d * 512);

        // ---- S^T per q-set: D[key_local][q] ----
        f32x16 sa[2];
        #pragma unroll
        for (int qs = 0; qs < 2; ++qs) {
            #pragma unroll
            for (int r = 0; r < 16; ++r) sa[qs][r] = 0.f;
            #pragma unroll
            for (int c = 0; c < 4; ++c)
                sa[qs] = __builtin_amdgcn_mfma_f32_32x32x16_bf16(kf[c], qf[qs][c], sa[qs], 0, 0, 0);
        }

        // ---- K frags for next tile (kf consumed above; regs reuse) ----
        if (kt + 64 < NN) {
            #pragma unroll
            for (int c = 0; c < 4; ++c)
                kf[c] = *(const bf16x8*)(kb + tb + 4096 + c * 512);
        }

        // ---- p = exp2(s), row-sum in VALU, pack to bf16 pairs ----
        unsigned dw[2][4][2];
        #pragma unroll
        for (int qs = 0; qs < 2; ++qs) {
            float t0 = 0.f;
            #pragma unroll
            for (int m4 = 0; m4 < 4; ++m4) {
                float p0 = __builtin_amdgcn_exp2f(sa[qs][m4 * 4 + 0]);
                float p1 = __builtin_amdgcn_exp2f(sa[qs][m4 * 4 + 1]);
                float p2 = __builtin_amdgcn_exp2f(sa[qs][m4 * 4 + 2]);
                float p3 = __builtin_amdgcn_exp2f(sa[qs][m4 * 4 + 3]);
                t0 += (p0 + p1) + (p2 + p3);
                dw[qs][m4][0] = pkbf(p0, p1);
                dw[qs][m4][1] = pkbf(p2, p3);
            }
            ts[qs] += t0;
        }

        // ---- PV MFMAs from register V frags ----
        #pragma unroll
        for (int kc = 0; kc < 2; ++kc) {
            #pragma unroll
            for (int qs = 0; qs < 2; ++qs) {
                int mlo = kc * 2;
                unsigned a0 = dw[qs][mlo][0],     a1 = dw[qs][mlo][1];
                unsigned b0 = dw[qs][mlo + 1][0], b1 = dw[qs][mlo + 1][1];
                union { unsigned u[4]; bf16x8 v; } pu;
#if HAVE_PLSWAP
                u32x2 r0 = __builtin_amdgcn_permlane32_swap(a0, b0, false, false);
                u32x2 r1 = __builtin_amdgcn_permlane32_swap(a1, b1, false, false);
                pu.u[0] = r0.x; pu.u[1] = r1.x; pu.u[2] = r0.y; pu.u[3] = r1.y;
#else
                unsigned own0 = hi ? b0 : a0, own1 = hi ? b1 : a1;
                unsigned snd0 = hi ? a0 : b0, snd1 = hi ? a1 : b1;
                unsigned rcv0 = __shfl_xor(snd0, 32, 64);
                unsigned rcv1 = __shfl_xor(snd1, 32, 64);
                pu.u[0] = hi ? rcv0 : own0;
                pu.u[1] = hi ? rcv1 : own1;
                pu.u[2] = hi ? own0 : rcv0;
                pu.u[3] = hi ? own1 : rcv1;
#endif
                #pragma unroll
                for (int d = 0; d < 2; ++d)
                    o[qs][d] = __builtin_amdgcn_mfma_f32_32x32x16_bf16(vfr[kc][d], pu.v, o[qs][d], 0, 0, 0);
            }
        }
    }

    // ---- epilogue: cross-kh reduction through LDS ----
    // O buffer: [q_l 128][16 chunks of 16B], chunk XOR-swizzled by (q_l & 15)
    float* Osm = (float*)smem;
    float* Ls  = (float*)(smem + 32768);
    float tsq[2];
    #pragma unroll
    for (int qs = 0; qs < 2; ++qs)
        tsq[qs] = ts[qs] + __shfl_xor(ts[qs], 32, 64);

    if (kh == 0) {
        #pragma unroll
        for (int qs = 0; qs < 2; ++qs) {
            int q_l = qh * 64 + qs * 32 + l32;
            #pragma unroll
            for (int d = 0; d < 2; ++d)
                #pragma unroll
                for (int m4 = 0; m4 < 4; ++m4) {
                    int ci = d * 8 + m4 * 2 + hi;
                    int pc = ci ^ (q_l & 15);
                    f32x4 v;
                    v[0] = o[qs][d][m4 * 4 + 0];
                    v[1] = o[qs][d][m4 * 4 + 1];
                    v[2] = o[qs][d][m4 * 4 + 2];
                    v[3] = o[qs][d][m4 * 4 + 3];
                    *(f32x4*)(Osm + q_l * 64 + pc * 4) = v;
                }
            if (!hi) Ls[q_l] = tsq[qs];
        }
    }
    __syncthreads();
    if (kh == 1) {
        #pragma unroll
        for (int qs = 0; qs < 2; ++qs) {
            int q_l = qh * 64 + qs * 32 + l32;
            #pragma unroll
            for (int d = 0; d < 2; ++d)
                #pragma unroll
                for (int m4 = 0; m4 < 4; ++m4) {
                    int ci = d * 8 + m4 * 2 + hi;
                    int pc = ci ^ (q_l & 15);
                    f32x4 v = *(const f32x4*)(Osm + q_l * 64 + pc * 4);
                    v[0] += o[qs][d][m4 * 4 + 0];
                    v[1] += o[qs][d][m4 * 4 + 1];
                    v[2] += o[qs][d][m4 * 4 + 2];
                    v[3] += o[qs][d][m4 * 4 + 3];
                    *(f32x4*)(Osm + q_l * 64 + pc * 4) = v;
                }
            if (!hi) Ls[q_l] += tsq[qs];
        }
    }
    __syncthreads();
    // ---- normalize + fully-coalesced store: 2048 x 16B chunks ----
    float* outb = out + ((size_t)hb * NN + q0) * DHH;
    #pragma unroll
    for (int i = 0; i < 8; ++i) {
        int g = tid + 256 * i;
        int q_l = g >> 4, ci = g & 15;
        int pc = ci ^ (q_l & 15);
        float inv = 1.0f / Ls[q_l];
        f32x4 v = *(const f32x4*)(Osm + q_l * 64 + pc * 4);
        v *= inv;
        *(f32x4*)(outb + g * 4) = v;
    }
}

extern "C" void kernel_launch(void* const* d_in, const int* in_sizes, int n_in,
                              void* d_out, int out_size, void* d_ws, size_t ws_size,
                              hipStream_t stream) {
    const float* data = (const float*)d_in[0];
    const float* Wq   = (const float*)d_in[1];
    const float* bq   = (const float*)d_in[2];
    const float* Wk   = (const float*)d_in[3];
    const float* bk   = (const float*)d_in[4];
    const float* Wv   = (const float*)d_in[5];
    const float* bv   = (const float*)d_in[6];
    float* out = (float*)d_out;

    char* ws = (char*)d_ws;
    bf16* xb = (bf16*)ws; ws += (size_t)8192 * 1024 * 2;       // 16 MB
    bf16* Bw = (bf16*)ws; ws += (size_t)3072 * 1024 * 2;       // 6 MB
    bf16* Qs = (bf16*)ws; ws += (size_t)HB * NN * DHH * 2;     // 16 MB
    bf16* Kf = (bf16*)ws; ws += (size_t)HB * NN * DHH * 2;     // 16 MB
    bf16* Vf = (bf16*)ws; ws += (size_t)HB * NN * DHH * 2;     // 16 MB

    pe_wtrans_kernel<<<11264, 256, 0, stream>>>(data, Wq, Wk, Wv, xb, Bw);
    gemm_qkv_fused<<<1536, 256, 0, stream>>>(xb, Bw, bq, bk, bv, Qs, Kf, Vf);
    attn_kernel<<<1024, 256, 0, stream>>>(Qs, Kf, Vf, out);
}

// Round 9
// 245.597 us; speedup vs baseline: 3.2437x; 3.2437x over previous
//
#include <hip/hip_runtime.h>
#include <hip/hip_bf16.h>

#define BB 4
#define NN 2048
#define DD 1024
#define HH 16
#define DHH 64
#define HB (HH*BB)   // 64

typedef __bf16 bf16;
typedef __bf16 bf16x4v __attribute__((ext_vector_type(4)));
typedef __bf16 bf16x8 __attribute__((ext_vector_type(8)));
typedef float f32x4 __attribute__((ext_vector_type(4)));
typedef float f32x16 __attribute__((ext_vector_type(16)));
typedef unsigned u32x2 __attribute__((ext_vector_type(2)));

#if __has_builtin(__builtin_amdgcn_permlane32_swap)
#define HAVE_PLSWAP 1
#else
#define HAVE_PLSWAP 0
#endif

// Q pre-scale: (1/sqrt(64)) * log2(e) so softmax runs in exp2 domain
#define QSCALE 0.18033688011112042f

__device__ __forceinline__ void async16(const void* g, void* l) {
    __builtin_amdgcn_global_load_lds(
        (const __attribute__((address_space(1))) unsigned int*)g,
        (__attribute__((address_space(3))) unsigned int*)l, 16, 0, 0);
}

__device__ __forceinline__ unsigned pkbf(float a, float b) {
    union { bf16 h[2]; unsigned u; } x;
    x.h[0] = (bf16)a; x.h[1] = (bf16)b;
    return x.u;
}

// ---------------- Fused PE-add + W-transpose (one launch) ----------------
// blocks [0, 8192): pe_add; blocks [8192, 11264): wtrans (3 x 32 x 32 tiles).
__global__ void pe_wtrans_kernel(const float* __restrict__ data,
                                 const float* __restrict__ Wq, const float* __restrict__ Wk,
                                 const float* __restrict__ Wv,
                                 bf16* __restrict__ xb, bf16* __restrict__ Bw) {
    __shared__ float s[32][33];
    int b = blockIdx.x;
    int tid = threadIdx.x;
    if (b < 8192) {
        int t = b * 256 + tid;
        int base = t * 4;
        int row = base >> 10;
        int d0 = base & 1023;
        int n = row & (NN - 1);
        const float LOG2_10000 = 13.287712379549449f;
        int pn = n & ~1;
        float denom_p = __builtin_amdgcn_exp2f((2.0f * (float)pn / (float)NN) * LOG2_10000);
        bool even_p = (n & 1) == 0;
        float4 dv = *(const float4*)(data + base);
        float din[4] = {dv.x, dv.y, dv.z, dv.w};
        bf16x4v ov;
        #pragma unroll
        for (int u = 0; u < 4; ++u) {
            int d = d0 + u;
            int di = d & ~1;
            float denom_i = __builtin_amdgcn_exp2f((2.0f * (float)di / (float)DD) * LOG2_10000);
            float a = (float)n / denom_i;
            float basev = ((d & 1) == 0) ? __sinf(a) : __cosf(a);
            float bm = (float)d / denom_p;
            float mult = even_p ? __sinf(bm) : __cosf(bm);
            ov[u] = (bf16)(din[u] + basev * mult);
        }
        *(bf16x4v*)(xb + base) = ov;
    } else {
        int bb = b - 8192;
        int bz = bb >> 10;            // 0..2
        int rem = bb & 1023;
        int by = (rem >> 5) * 32;     // k0
        int bx = (rem & 31) * 32;     // n0
        const float* W = (bz == 0) ? Wq : (bz == 1) ? Wk : Wv;
        bf16* Wt = Bw + (size_t)bz * 1024 * 1024;
        int tx = tid & 31, ty = tid >> 5;   // (32,8)
        #pragma unroll
        for (int i = 0; i < 32; i += 8)
            s[ty + i][tx] = W[(by + ty + i) * DD + bx + tx];
        __syncthreads();
        #pragma unroll
        for (int i = 0; i < 32; i += 8)
            Wt[(size_t)(bx + ty + i) * DD + by + tx] = (bf16)s[tx][ty + i];
    }
}

// ---------------- Fused QKV GEMM (32x32x16, dbuf) ----------------
// K and V outputs are emitted in ATTENTION FRAGMENT ORDER so the attention kernel can do
// fully-coalesced per-wave global loads with no LDS staging and no barriers:
//   Kf[hb][tile(32)][kh(2)][c(4)][lane(64)][8 bf16]   (8KB per tile image)
//   Vf[hb][tile(32)][kh(2)][kc(2)][d(2)][lane(64)][8] (8KB per tile image)
// lane = hi*32 + l32; Kf element = K[n = tile*64+kh*32+l32][dh = c*16+hi*8+e];
// Vf element = V^T[dh = d*32+l32][key = tile*64+(kh*4+kc*2+hi)*8+e].
__launch_bounds__(256)
__global__ void gemm_qkv_fused(const bf16* __restrict__ A,   // [8192][1024]
                               const bf16* __restrict__ Bw,  // [3072][1024]
                               const float* __restrict__ bq, const float* __restrict__ bk,
                               const float* __restrict__ bv,
                               bf16* __restrict__ Qs, bf16* __restrict__ Kf,
                               bf16* __restrict__ Vf) {
    __shared__ char smem[36864];   // staging: 2 x 16KB ; V epilogue: 128x130 bf16 = 33280B
    int tid = threadIdx.x;
    int w = tid >> 6, lane = tid & 63, l32 = lane & 31, hi = lane >> 5;
    int bi = blockIdx.x;
    int bn = bi >> 6;
    int bm = (bi & 7) * 8 + ((bi >> 3) & 7);   // XCD-clustered A-row tiles
    int m0 = bm * 128, n0 = bn * 128;
    int wm = (w & 1) * 64, wn = (w >> 1) * 64;

    int srow = tid >> 2;
    int g4 = (tid & 3) ^ (srow & 3);           // XOR-4 swizzle
    const bf16* aS0 = A + (size_t)(m0 + srow) * DD + g4 * 8;
    const bf16* aS1 = aS0 + (size_t)64 * DD;
    const bf16* bS0 = Bw + (size_t)(n0 + srow) * DD + g4 * 8;
    const bf16* bS1 = bS0 + (size_t)64 * DD;

    f32x16 acc[2][2];
    #pragma unroll
    for (int i = 0; i < 2; ++i)
        #pragma unroll
        for (int j = 0; j < 2; ++j)
            #pragma unroll
            for (int r = 0; r < 16; ++r) acc[i][j][r] = 0.f;

    async16(aS0, smem + w * 1024);
    async16(aS1, smem + 4096 + w * 1024);
    async16(bS0, smem + 8192 + w * 1024);
    async16(bS1, smem + 12288 + w * 1024);
    __syncthreads();

    for (int kk = 0; kk < DD; kk += 32) {
        char* buf  = smem + ((kk >> 5) & 1) * 16384;
        char* nbuf = smem + (((kk >> 5) & 1) ^ 1) * 16384;
        if (kk + 32 < DD) {
            async16(aS0 + kk + 32, nbuf + w * 1024);
            async16(aS1 + kk + 32, nbuf + 4096 + w * 1024);
            async16(bS0 + kk + 32, nbuf + 8192 + w * 1024);
            async16(bS1 + kk + 32, nbuf + 12288 + w * 1024);
        }
        const char* As = buf;
        const char* Bs = buf + 8192;
        bf16x8 af[2][2], bfr[2][2];
        #pragma unroll
        for (int mt = 0; mt < 2; ++mt) {
            int row = wm + mt * 32 + l32;
            #pragma unroll
            for (int kc = 0; kc < 2; ++kc)
                af[mt][kc] = *(const bf16x8*)(As + row * 64 + ((kc * 2 + hi) ^ (l32 & 3)) * 16);
        }
        #pragma unroll
        for (int nt = 0; nt < 2; ++nt) {
            int row = wn + nt * 32 + l32;
            #pragma unroll
            for (int kc = 0; kc < 2; ++kc)
                bfr[nt][kc] = *(const bf16x8*)(Bs + row * 64 + ((kc * 2 + hi) ^ (l32 & 3)) * 16);
        }
        #pragma unroll
        for (int mt = 0; mt < 2; ++mt)
            #pragma unroll
            for (int nt = 0; nt < 2; ++nt)
                #pragma unroll
                for (int kc = 0; kc < 2; ++kc)
                    acc[mt][nt] = __builtin_amdgcn_mfma_f32_32x32x16_bf16(
                        af[mt][kc], bfr[nt][kc], acc[mt][nt], 0, 0, 0);
        __syncthreads();
    }

    int mat = n0 >> 10;  // uniform per block (bn<8: Q, <16: K, else V)
    if (mat == 0) {
        #pragma unroll
        for (int nt = 0; nt < 2; ++nt) {
            int ncol = (n0 + wn + nt * 32 + l32) & 1023;
            float bias = bq[ncol];
            int h = ncol >> 6, dh = ncol & 63;
            #pragma unroll
            for (int mt = 0; mt < 2; ++mt) {
                int rowbase = m0 + wm + mt * 32 + 4 * hi;
                #pragma unroll
                for (int m4 = 0; m4 < 4; ++m4) {
                    #pragma unroll
                    for (int rr = 0; rr < 4; ++rr) {
                        int mrow = rowbase + 8 * m4 + rr;
                        int b_ = mrow >> 11, nn_ = mrow & 2047;
                        int hbi = h * BB + b_;
                        float v = acc[mt][nt][m4 * 4 + rr] + bias;
                        Qs[((size_t)hbi * NN + nn_) * DHH + dh] = (bf16)(v * QSCALE);
                    }
                }
            }
        }
    } else if (mat == 1) {
        // ---- K: scalar stores into fragment-order Kf ----
        #pragma unroll
        for (int nt = 0; nt < 2; ++nt) {
            int ncol = (n0 + wn + nt * 32 + l32) & 1023;
            float bias = bk[ncol];
            int h = ncol >> 6, dh = ncol & 63;
            int c = dh >> 4, hi2 = (dh >> 3) & 1, e = dh & 7;
            #pragma unroll
            for (int mt = 0; mt < 2; ++mt) {
                int rowbase = m0 + wm + mt * 32 + 4 * hi;
                #pragma unroll
                for (int m4 = 0; m4 < 4; ++m4) {
                    #pragma unroll
                    for (int rr = 0; rr < 4; ++rr) {
                        int mrow = rowbase + 8 * m4 + rr;
                        int b_ = mrow >> 11, nn_ = mrow & 2047;
                        int hbi = h * BB + b_;
                        int T = nn_ >> 6, r = nn_ & 63;
                        int khk = r >> 5, l32k = r & 31;
                        float v = acc[mt][nt][m4 * 4 + rr] + bias;
                        Kf[((size_t)(hbi * 32 + T)) * 4096 + khk * 2048 + c * 512 +
                           (hi2 * 32 + l32k) * 8 + e] = (bf16)v;
                    }
                }
            }
        }
    } else {
        // ---- V: bounce through LDS, then lane-contiguous 16B stores into Vf ----
        bf16* vl = (bf16*)smem;
        #pragma unroll
        for (int nt = 0; nt < 2; ++nt) {
            int ncol_l = wn + nt * 32 + l32;
            float bias = bv[(n0 + ncol_l) & 1023];
            #pragma unroll
            for (int mt = 0; mt < 2; ++mt) {
                int m_base = wm + mt * 32 + 4 * hi;
                #pragma unroll
                for (int m4 = 0; m4 < 4; ++m4) {
                    bf16x4v q;
                    #pragma unroll
                    for (int rr = 0; rr < 4; ++rr)
                        q[rr] = (bf16)(acc[mt][nt][m4 * 4 + rr] + bias);
                    *(bf16x4v*)(vl + ncol_l * 130 + m_base + 8 * m4) = q;
                }
            }
        }
        __syncthreads();
        int b_ = m0 >> 11;
        int tile0 = (m0 & 2047) >> 6;
        int h0 = (n0 & 1023) >> 6;
        // 2048 16B-units: [hh(2)][tt(2)][u(512)], u = kh*256 + kc*128 + d*64 + lane
        #pragma unroll
        for (int j = 0; j < 8; ++j) {
            int g = tid + 256 * j;
            int hh = g >> 10, tt = (g >> 9) & 1, u = g & 511;
            int khv = u >> 8, kcv = (u >> 7) & 1, dv = (u >> 6) & 1, lanev = u & 63;
            int hiv = lanev >> 5, l32v = lanev & 31;
            int col = hh * 64 + dv * 32 + l32v;
            int chunk = khv * 4 + kcv * 2 + hiv;
            bf16x8 vv = *(const bf16x8*)(vl + col * 130 + tt * 64 + chunk * 8);
            int hb2 = (h0 + hh) * BB + b_;
            *(bf16x8*)(Vf + ((size_t)(hb2 * 32 + tile0 + tt)) * 4096 + (size_t)u * 8) = vv;
        }
    }
}

// ---------------- Flash attention: barrier-free, fragment-order global loads ----------------
// K/V are pre-arranged by the GEMM in per-wave fragment order, so each fragment load is
// base + lane*16 -- one coalesced 1KB global_load_dwordx4, L2-resident. No LDS staging, no
// main-loop barriers, no bank conflicts; waves drift freely.
// launch_bounds NOTE (rounds 6+8 post-mortems): this toolchain's VGPR cap is ~256/arg2
// regardless of block size ((512,4)->64, (256,4)->64, (256,3)->84, (512,2)->128 measured).
// Kernel needs ~90 VGPRs -> arg2=2 (cap 128). Round 8's (256,4) capped at 64 and spilled
// the accumulators (3GB scratch traffic, 637us); the layout itself verified correct.
__launch_bounds__(256, 2)
__global__ void attn_kernel(const bf16* __restrict__ Qs,   // [hb][n][dh], pre-scaled
                            const bf16* __restrict__ Kf,   // fragment order
                            const bf16* __restrict__ Vf,   // fragment order
                            float* __restrict__ out) {     // [hb][n][dh]
    __shared__ char smem[33280];   // epilogue only: O 32KB + Ls 512B
    int tid = threadIdx.x;
    int w = tid >> 6, lane = tid & 63, l32 = lane & 31, hi = lane >> 5;
    int qh = w & 1, kh = w >> 1;
    int bi = blockIdx.x;
    int xcd = bi & 7, jj = bi >> 3;
    int hb = xcd * 8 + (jj & 7);
    int qb = jj >> 3;
    int q0 = qb * 128;

    // Q B-frags for 2 q-sets: cols q0 + qh*64 + qs*32 + l32, k = dh c*16 + hi*8 + j
    bf16x8 qf[2][4];
    #pragma unroll
    for (int qs = 0; qs < 2; ++qs) {
        const bf16* qbase = Qs + ((size_t)hb * NN + q0 + qh * 64 + qs * 32 + l32) * DHH + hi * 8;
        #pragma unroll
        for (int c = 0; c < 4; ++c)
            qf[qs][c] = *(const bf16x8*)(qbase + c * 16);
    }

    // fragment-order bases: per tile stride 4096 bf16 (8KB)
    const bf16* kb = Kf + (size_t)hb * 32 * 4096 + kh * 2048 + lane * 8;
    const bf16* vb = Vf + (size_t)hb * 32 * 4096 + kh * 2048 + lane * 8;

    f32x16 o[2][2];   // [qs][d] partial over this wave's keys
    #pragma unroll
    for (int qs = 0; qs < 2; ++qs)
        #pragma unroll
        for (int d = 0; d < 2; ++d)
            #pragma unroll
            for (int r = 0; r < 16; ++r) o[qs][d][r] = 0.f;
    float ts[2] = {0.f, 0.f};

    // K frags for tile 0
    bf16x8 kf[4];
    #pragma unroll
    for (int c = 0; c < 4; ++c)
        kf[c] = *(const bf16x8*)(kb + c * 512);

    for (int kt = 0; kt < NN; kt += 64) {
        int tb = (kt >> 6) * 4096;

        // ---- V frags: issue early, consumed after QK+softmax ----
        bf16x8 vfr[2][2];
        #pragma unroll
        for (int kc = 0; kc < 2; ++kc)
            #pragma unroll
            for (int d = 0; d < 2; ++d)
                vfr[kc][d] = *(const bf16x8*)(vb + tb + kc * 1024 + d * 512);

        // ---- S^T per q-set: D[key_local][q] ----
        f32x16 sa[2];
        #pragma unroll
        for (int qs = 0; qs < 2; ++qs) {
            #pragma unroll
            for (int r = 0; r < 16; ++r) sa[qs][r] = 0.f;
            #pragma unroll
            for (int c = 0; c < 4; ++c)
                sa[qs] = __builtin_amdgcn_mfma_f32_32x32x16_bf16(kf[c], qf[qs][c], sa[qs], 0, 0, 0);
        }

        // ---- K frags for next tile (kf consumed above; regs reuse) ----
        if (kt + 64 < NN) {
            #pragma unroll
            for (int c = 0; c < 4; ++c)
                kf[c] = *(const bf16x8*)(kb + tb + 4096 + c * 512);
        }

        // ---- p = exp2(s), row-sum in VALU, pack to bf16 pairs ----
        unsigned dw[2][4][2];
        #pragma unroll
        for (int qs = 0; qs < 2; ++qs) {
            float t0 = 0.f;
            #pragma unroll
            for (int m4 = 0; m4 < 4; ++m4) {
                float p0 = __builtin_amdgcn_exp2f(sa[qs][m4 * 4 + 0]);
                float p1 = __builtin_amdgcn_exp2f(sa[qs][m4 * 4 + 1]);
                float p2 = __builtin_amdgcn_exp2f(sa[qs][m4 * 4 + 2]);
                float p3 = __builtin_amdgcn_exp2f(sa[qs][m4 * 4 + 3]);
                t0 += (p0 + p1) + (p2 + p3);
                dw[qs][m4][0] = pkbf(p0, p1);
                dw[qs][m4][1] = pkbf(p2, p3);
            }
            ts[qs] += t0;
        }

        // ---- PV MFMAs from register V frags ----
        #pragma unroll
        for (int kc = 0; kc < 2; ++kc) {
            #pragma unroll
            for (int qs = 0; qs < 2; ++qs) {
                int mlo = kc * 2;
                unsigned a0 = dw[qs][mlo][0],     a1 = dw[qs][mlo][1];
                unsigned b0 = dw[qs][mlo + 1][0], b1 = dw[qs][mlo + 1][1];
                union { unsigned u[4]; bf16x8 v; } pu;
#if HAVE_PLSWAP
                u32x2 r0 = __builtin_amdgcn_permlane32_swap(a0, b0, false, false);
                u32x2 r1 = __builtin_amdgcn_permlane32_swap(a1, b1, false, false);
                pu.u[0] = r0.x; pu.u[1] = r1.x; pu.u[2] = r0.y; pu.u[3] = r1.y;
#else
                unsigned own0 = hi ? b0 : a0, own1 = hi ? b1 : a1;
                unsigned snd0 = hi ? a0 : b0, snd1 = hi ? a1 : b1;
                unsigned rcv0 = __shfl_xor(snd0, 32, 64);
                unsigned rcv1 = __shfl_xor(snd1, 32, 64);
                pu.u[0] = hi ? rcv0 : own0;
                pu.u[1] = hi ? rcv1 : own1;
                pu.u[2] = hi ? own0 : rcv0;
                pu.u[3] = hi ? own1 : rcv1;
#endif
                #pragma unroll
                for (int d = 0; d < 2; ++d)
                    o[qs][d] = __builtin_amdgcn_mfma_f32_32x32x16_bf16(vfr[kc][d], pu.v, o[qs][d], 0, 0, 0);
            }
        }
    }

    // ---- epilogue: cross-kh reduction through LDS ----
    // O buffer: [q_l 128][16 chunks of 16B], chunk XOR-swizzled by (q_l & 15)
    float* Osm = (float*)smem;
    float* Ls  = (float*)(smem + 32768);
    float tsq[2];
    #pragma unroll
    for (int qs = 0; qs < 2; ++qs)
        tsq[qs] = ts[qs] + __shfl_xor(ts[qs], 32, 64);

    if (kh == 0) {
        #pragma unroll
        for (int qs = 0; qs < 2; ++qs) {
            int q_l = qh * 64 + qs * 32 + l32;
            #pragma unroll
            for (int d = 0; d < 2; ++d)
                #pragma unroll
                for (int m4 = 0; m4 < 4; ++m4) {
                    int ci = d * 8 + m4 * 2 + hi;
                    int pc = ci ^ (q_l & 15);
                    f32x4 v;
                    v[0] = o[qs][d][m4 * 4 + 0];
                    v[1] = o[qs][d][m4 * 4 + 1];
                    v[2] = o[qs][d][m4 * 4 + 2];
                    v[3] = o[qs][d][m4 * 4 + 3];
                    *(f32x4*)(Osm + q_l * 64 + pc * 4) = v;
                }
            if (!hi) Ls[q_l] = tsq[qs];
        }
    }
    __syncthreads();
    if (kh == 1) {
        #pragma unroll
        for (int qs = 0; qs < 2; ++qs) {
            int q_l = qh * 64 + qs * 32 + l32;
            #pragma unroll
            for (int d = 0; d < 2; ++d)
                #pragma unroll
                for (int m4 = 0; m4 < 4; ++m4) {
                    int ci = d * 8 + m4 * 2 + hi;
                    int pc = ci ^ (q_l & 15);
                    f32x4 v = *(const f32x4*)(Osm + q_l * 64 + pc * 4);
                    v[0] += o[qs][d][m4 * 4 + 0];
                    v[1] += o[qs][d][m4 * 4 + 1];
                    v[2] += o[qs][d][m4 * 4 + 2];
                    v[3] += o[qs][d][m4 * 4 + 3];
                    *(f32x4*)(Osm + q_l * 64 + pc * 4) = v;
                }
            if (!hi) Ls[q_l] += tsq[qs];
        }
    }
    __syncthreads();
    // ---- normalize + fully-coalesced store: 2048 x 16B chunks ----
    float* outb = out + ((size_t)hb * NN + q0) * DHH;
    #pragma unroll
    for (int i = 0; i < 8; ++i) {
        int g = tid + 256 * i;
        int q_l = g >> 4, ci = g & 15;
        int pc = ci ^ (q_l & 15);
        float inv = 1.0f / Ls[q_l];
        f32x4 v = *(const f32x4*)(Osm + q_l * 64 + pc * 4);
        v *= inv;
        *(f32x4*)(outb + g * 4) = v;
    }
}

extern "C" void kernel_launch(void* const* d_in, const int* in_sizes, int n_in,
                              void* d_out, int out_size, void* d_ws, size_t ws_size,
                              hipStream_t stream) {
    const float* data = (const float*)d_in[0];
    const float* Wq   = (const float*)d_in[1];
    const float* bq   = (const float*)d_in[2];
    const float* Wk   = (const float*)d_in[3];
    const float* bk   = (const float*)d_in[4];
    const float* Wv   = (const float*)d_in[5];
    const float* bv   = (const float*)d_in[6];
    float* out = (float*)d_out;

    char* ws = (char*)d_ws;
    bf16* xb = (bf16*)ws; ws += (size_t)8192 * 1024 * 2;       // 16 MB
    bf16* Bw = (bf16*)ws; ws += (size_t)3072 * 1024 * 2;       // 6 MB
    bf16* Qs = (bf16*)ws; ws += (size_t)HB * NN * DHH * 2;     // 16 MB
    bf16* Kf = (bf16*)ws; ws += (size_t)HB * NN * DHH * 2;     // 16 MB
    bf16* Vf = (bf16*)ws; ws += (size_t)HB * NN * DHH * 2;     // 16 MB

    pe_wtrans_kernel<<<11264, 256, 0, stream>>>(data, Wq, Wk, Wv, xb, Bw);
    gemm_qkv_fused<<<1536, 256, 0, stream>>>(xb, Bw, bq, bk, bv, Qs, Kf, Vf);
    attn_kernel<<<1024, 256, 0, stream>>>(Qs, Kf, Vf, out);
}

// Round 10
// 240.268 us; speedup vs baseline: 3.3156x; 1.0222x over previous
//
#include <hip/hip_runtime.h>
#include <hip/hip_bf16.h>

#define BB 4
#define NN 2048
#define DD 1024
#define HH 16
#define DHH 64
#define HB (HH*BB)   // 64

typedef __bf16 bf16;
typedef __bf16 bf16x4v __attribute__((ext_vector_type(4)));
typedef __bf16 bf16x8 __attribute__((ext_vector_type(8)));
typedef float f32x4 __attribute__((ext_vector_type(4)));
typedef float f32x16 __attribute__((ext_vector_type(16)));
typedef unsigned u32x2 __attribute__((ext_vector_type(2)));

#if __has_builtin(__builtin_amdgcn_permlane32_swap)
#define HAVE_PLSWAP 1
#else
#define HAVE_PLSWAP 0
#endif

// Q pre-scale: (1/sqrt(64)) * log2(e) so softmax runs in exp2 domain
#define QSCALE 0.18033688011112042f

__device__ __forceinline__ void async16(const void* g, void* l) {
    __builtin_amdgcn_global_load_lds(
        (const __attribute__((address_space(1))) unsigned int*)g,
        (__attribute__((address_space(3))) unsigned int*)l, 16, 0, 0);
}

__device__ __forceinline__ unsigned pkbf(float a, float b) {
    union { bf16 h[2]; unsigned u; } x;
    x.h[0] = (bf16)a; x.h[1] = (bf16)b;
    return x.u;
}

// ---------------- Fused PE-add + W-transpose (one launch) ----------------
// blocks [0, 8192): pe_add; blocks [8192, 11264): wtrans (3 x 32 x 32 tiles).
__global__ void pe_wtrans_kernel(const float* __restrict__ data,
                                 const float* __restrict__ Wq, const float* __restrict__ Wk,
                                 const float* __restrict__ Wv,
                                 bf16* __restrict__ xb, bf16* __restrict__ Bw) {
    __shared__ float s[32][33];
    int b = blockIdx.x;
    int tid = threadIdx.x;
    if (b < 8192) {
        int t = b * 256 + tid;
        int base = t * 4;
        int row = base >> 10;
        int d0 = base & 1023;
        int n = row & (NN - 1);
        const float LOG2_10000 = 13.287712379549449f;
        int pn = n & ~1;
        float denom_p = __builtin_amdgcn_exp2f((2.0f * (float)pn / (float)NN) * LOG2_10000);
        bool even_p = (n & 1) == 0;
        float4 dv = *(const float4*)(data + base);
        float din[4] = {dv.x, dv.y, dv.z, dv.w};
        bf16x4v ov;
        #pragma unroll
        for (int u = 0; u < 4; ++u) {
            int d = d0 + u;
            int di = d & ~1;
            float denom_i = __builtin_amdgcn_exp2f((2.0f * (float)di / (float)DD) * LOG2_10000);
            float a = (float)n / denom_i;
            float basev = ((d & 1) == 0) ? __sinf(a) : __cosf(a);
            float bm = (float)d / denom_p;
            float mult = even_p ? __sinf(bm) : __cosf(bm);
            ov[u] = (bf16)(din[u] + basev * mult);
        }
        *(bf16x4v*)(xb + base) = ov;
    } else {
        int bb = b - 8192;
        int bz = bb >> 10;            // 0..2
        int rem = bb & 1023;
        int by = (rem >> 5) * 32;     // k0
        int bx = (rem & 31) * 32;     // n0
        const float* W = (bz == 0) ? Wq : (bz == 1) ? Wk : Wv;
        bf16* Wt = Bw + (size_t)bz * 1024 * 1024;
        int tx = tid & 31, ty = tid >> 5;   // (32,8)
        #pragma unroll
        for (int i = 0; i < 32; i += 8)
            s[ty + i][tx] = W[(by + ty + i) * DD + bx + tx];
        __syncthreads();
        #pragma unroll
        for (int i = 0; i < 32; i += 8)
            Wt[(size_t)(bx + ty + i) * DD + by + tx] = (bf16)s[tx][ty + i];
    }
}

// ---------------- Fused QKV GEMM (32x32x16, dbuf) ----------------
// K and V outputs are emitted in ATTENTION FRAGMENT ORDER so the attention kernel can do
// fully-coalesced per-wave global loads with no LDS staging and no barriers:
//   Kf[hb][tile(32)][kh(2)][c(4)][lane(64)][8 bf16]   (8KB per tile image)
//   Vf[hb][tile(32)][kh(2)][kc(2)][d(2)][lane(64)][8] (8KB per tile image)
// lane = hi*32 + l32; Kf element = K[n = tile*64+kh*32+l32][dh = c*16+hi*8+e];
// Vf element = V^T[dh = d*32+l32][key = tile*64+(kh*4+kc*2+hi)*8+e].
// BOTH K and V bounce through LDS so all global stores are lane-contiguous 16B
// (round-9 post-mortem: K's direct scalar scattered stores cost the gemm ~7us).
__launch_bounds__(256)
__global__ void gemm_qkv_fused(const bf16* __restrict__ A,   // [8192][1024]
                               const bf16* __restrict__ Bw,  // [3072][1024]
                               const float* __restrict__ bq, const float* __restrict__ bk,
                               const float* __restrict__ bv,
                               bf16* __restrict__ Qs, bf16* __restrict__ Kf,
                               bf16* __restrict__ Vf) {
    __shared__ char smem[36864];   // staging: 2 x 16KB ; epilogue bounce: K 128x132 / V 128x130
    int tid = threadIdx.x;
    int w = tid >> 6, lane = tid & 63, l32 = lane & 31, hi = lane >> 5;
    int bi = blockIdx.x;
    int bn = bi >> 6;
    int bm = (bi & 7) * 8 + ((bi >> 3) & 7);   // XCD-clustered A-row tiles
    int m0 = bm * 128, n0 = bn * 128;
    int wm = (w & 1) * 64, wn = (w >> 1) * 64;

    int srow = tid >> 2;
    int g4 = (tid & 3) ^ (srow & 3);           // XOR-4 swizzle
    const bf16* aS0 = A + (size_t)(m0 + srow) * DD + g4 * 8;
    const bf16* aS1 = aS0 + (size_t)64 * DD;
    const bf16* bS0 = Bw + (size_t)(n0 + srow) * DD + g4 * 8;
    const bf16* bS1 = bS0 + (size_t)64 * DD;

    f32x16 acc[2][2];
    #pragma unroll
    for (int i = 0; i < 2; ++i)
        #pragma unroll
        for (int j = 0; j < 2; ++j)
            #pragma unroll
            for (int r = 0; r < 16; ++r) acc[i][j][r] = 0.f;

    async16(aS0, smem + w * 1024);
    async16(aS1, smem + 4096 + w * 1024);
    async16(bS0, smem + 8192 + w * 1024);
    async16(bS1, smem + 12288 + w * 1024);
    __syncthreads();

    for (int kk = 0; kk < DD; kk += 32) {
        char* buf  = smem + ((kk >> 5) & 1) * 16384;
        char* nbuf = smem + (((kk >> 5) & 1) ^ 1) * 16384;
        if (kk + 32 < DD) {
            async16(aS0 + kk + 32, nbuf + w * 1024);
            async16(aS1 + kk + 32, nbuf + 4096 + w * 1024);
            async16(bS0 + kk + 32, nbuf + 8192 + w * 1024);
            async16(bS1 + kk + 32, nbuf + 12288 + w * 1024);
        }
        const char* As = buf;
        const char* Bs = buf + 8192;
        bf16x8 af[2][2], bfr[2][2];
        #pragma unroll
        for (int mt = 0; mt < 2; ++mt) {
            int row = wm + mt * 32 + l32;
            #pragma unroll
            for (int kc = 0; kc < 2; ++kc)
                af[mt][kc] = *(const bf16x8*)(As + row * 64 + ((kc * 2 + hi) ^ (l32 & 3)) * 16);
        }
        #pragma unroll
        for (int nt = 0; nt < 2; ++nt) {
            int row = wn + nt * 32 + l32;
            #pragma unroll
            for (int kc = 0; kc < 2; ++kc)
                bfr[nt][kc] = *(const bf16x8*)(Bs + row * 64 + ((kc * 2 + hi) ^ (l32 & 3)) * 16);
        }
        #pragma unroll
        for (int mt = 0; mt < 2; ++mt)
            #pragma unroll
            for (int nt = 0; nt < 2; ++nt)
                #pragma unroll
                for (int kc = 0; kc < 2; ++kc)
                    acc[mt][nt] = __builtin_amdgcn_mfma_f32_32x32x16_bf16(
                        af[mt][kc], bfr[nt][kc], acc[mt][nt], 0, 0, 0);
        __syncthreads();
    }

    int mat = n0 >> 10;  // uniform per block (bn<8: Q, <16: K, else V)
    if (mat == 0) {
        #pragma unroll
        for (int nt = 0; nt < 2; ++nt) {
            int ncol = (n0 + wn + nt * 32 + l32) & 1023;
            float bias = bq[ncol];
            int h = ncol >> 6, dh = ncol & 63;
            #pragma unroll
            for (int mt = 0; mt < 2; ++mt) {
                int rowbase = m0 + wm + mt * 32 + 4 * hi;
                #pragma unroll
                for (int m4 = 0; m4 < 4; ++m4) {
                    #pragma unroll
                    for (int rr = 0; rr < 4; ++rr) {
                        int mrow = rowbase + 8 * m4 + rr;
                        int b_ = mrow >> 11, nn_ = mrow & 2047;
                        int hbi = h * BB + b_;
                        float v = acc[mt][nt][m4 * 4 + rr] + bias;
                        Qs[((size_t)hbi * NN + nn_) * DHH + dh] = (bf16)(v * QSCALE);
                    }
                }
            }
        }
    } else if (mat == 1) {
        // ---- K: bounce through LDS [key 128][dh 132-pad], then lane-contiguous 16B
        //      stores into Kf (1KB contiguous per wave per iteration). ----
        bf16* kl = (bf16*)smem;   // 128 x 132 bf16 = 33792 B
        #pragma unroll
        for (int nt = 0; nt < 2; ++nt) {
            int ncol_l = wn + nt * 32 + l32;          // local dh-col 0..127
            float bias = bk[(n0 + ncol_l) & 1023];
            #pragma unroll
            for (int mt = 0; mt < 2; ++mt) {
                int m_base = wm + mt * 32 + 4 * hi;
                #pragma unroll
                for (int m4 = 0; m4 < 4; ++m4) {
                    #pragma unroll
                    for (int rr = 0; rr < 4; ++rr) {
                        int mrow_l = m_base + 8 * m4 + rr;   // local key-row 0..127
                        kl[mrow_l * 132 + ncol_l] = (bf16)(acc[mt][nt][m4 * 4 + rr] + bias);
                    }
                }
            }
        }
        __syncthreads();
        int b_ = m0 >> 11;
        int tile0 = (m0 & 2047) >> 6;
        int h0 = (n0 & 1023) >> 6;
        // 2048 16B-units: g = [hh(2)][T(2)][kh(2)][c(4)][hi2(2)][l32k(32)]
        #pragma unroll
        for (int j = 0; j < 8; ++j) {
            int g = tid + 256 * j;
            int hh = g >> 10, T = (g >> 9) & 1, khk = (g >> 8) & 1;
            int c = (g >> 6) & 3, hi2 = (g >> 5) & 1, l32k = g & 31;
            int row = T * 64 + khk * 32 + l32k;            // local key
            int col = hh * 64 + c * 16 + hi2 * 8;          // local dh (8 contiguous)
            bf16x8 kv = *(const bf16x8*)(kl + row * 132 + col);
            int hbi = (h0 + hh) * BB + b_;
            *(bf16x8*)(Kf + ((size_t)(hbi * 32 + tile0 + T)) * 4096 + khk * 2048 +
                       c * 512 + (hi2 * 32 + l32k) * 8) = kv;
        }
    } else {
        // ---- V: bounce through LDS, then lane-contiguous 16B stores into Vf ----
        bf16* vl = (bf16*)smem;
        #pragma unroll
        for (int nt = 0; nt < 2; ++nt) {
            int ncol_l = wn + nt * 32 + l32;
            float bias = bv[(n0 + ncol_l) & 1023];
            #pragma unroll
            for (int mt = 0; mt < 2; ++mt) {
                int m_base = wm + mt * 32 + 4 * hi;
                #pragma unroll
                for (int m4 = 0; m4 < 4; ++m4) {
                    bf16x4v q;
                    #pragma unroll
                    for (int rr = 0; rr < 4; ++rr)
                        q[rr] = (bf16)(acc[mt][nt][m4 * 4 + rr] + bias);
                    *(bf16x4v*)(vl + ncol_l * 130 + m_base + 8 * m4) = q;
                }
            }
        }
        __syncthreads();
        int b_ = m0 >> 11;
        int tile0 = (m0 & 2047) >> 6;
        int h0 = (n0 & 1023) >> 6;
        // 2048 16B-units: [hh(2)][tt(2)][u(512)], u = kh*256 + kc*128 + d*64 + lane
        #pragma unroll
        for (int j = 0; j < 8; ++j) {
            int g = tid + 256 * j;
            int hh = g >> 10, tt = (g >> 9) & 1, u = g & 511;
            int khv = u >> 8, kcv = (u >> 7) & 1, dv = (u >> 6) & 1, lanev = u & 63;
            int hiv = lanev >> 5, l32v = lanev & 31;
            int col = hh * 64 + dv * 32 + l32v;
            int chunk = khv * 4 + kcv * 2 + hiv;
            bf16x8 vv = *(const bf16x8*)(vl + col * 130 + tt * 64 + chunk * 8);
            int hb2 = (h0 + hh) * BB + b_;
            *(bf16x8*)(Vf + ((size_t)(hb2 * 32 + tile0 + tt)) * 4096 + (size_t)u * 8) = vv;
        }
    }
}

// ---------------- Flash attention: barrier-free, fragment-order global loads ----------------
// K/V are pre-arranged by the GEMM in per-wave fragment order, so each fragment load is
// base + lane*16 -- one coalesced 1KB global_load_dwordx4, L2-resident. No LDS staging, no
// main-loop barriers, no bank conflicts; waves drift freely.
// launch_bounds NOTE (rounds 6+8 post-mortems): this toolchain's VGPR cap is ~256/arg2
// regardless of block size ((512,4)->64, (256,4)->64, (256,3)->84, (512,2)->128 measured).
// Kernel needs ~100 VGPRs -> arg2=2 (cap 128). Verified round 9: VGPR=100, no spill,
// conflicts 0, attn 83.4us.
__launch_bounds__(256, 2)
__global__ void attn_kernel(const bf16* __restrict__ Qs,   // [hb][n][dh], pre-scaled
                            const bf16* __restrict__ Kf,   // fragment order
                            const bf16* __restrict__ Vf,   // fragment order
                            float* __restrict__ out) {     // [hb][n][dh]
    __shared__ char smem[33280];   // epilogue only: O 32KB + Ls 512B
    int tid = threadIdx.x;
    int w = tid >> 6, lane = tid & 63, l32 = lane & 31, hi = lane >> 5;
    int qh = w & 1, kh = w >> 1;
    int bi = blockIdx.x;
    int xcd = bi & 7, jj = bi >> 3;
    int hb = xcd * 8 + (jj & 7);
    int qb = jj >> 3;
    int q0 = qb * 128;

    // Q B-frags for 2 q-sets: cols q0 + qh*64 + qs*32 + l32, k = dh c*16 + hi*8 + j
    bf16x8 qf[2][4];
    #pragma unroll
    for (int qs = 0; qs < 2; ++qs) {
        const bf16* qbase = Qs + ((size_t)hb * NN + q0 + qh * 64 + qs * 32 + l32) * DHH + hi * 8;
        #pragma unroll
        for (int c = 0; c < 4; ++c)
            qf[qs][c] = *(const bf16x8*)(qbase + c * 16);
    }

    // fragment-order bases: per tile stride 4096 bf16 (8KB)
    const bf16* kb = Kf + (size_t)hb * 32 * 4096 + kh * 2048 + lane * 8;
    const bf16* vb = Vf + (size_t)hb * 32 * 4096 + kh * 2048 + lane * 8;

    f32x16 o[2][2];   // [qs][d] partial over this wave's keys
    #pragma unroll
    for (int qs = 0; qs < 2; ++qs)
        #pragma unroll
        for (int d = 0; d < 2; ++d)
            #pragma unroll
            for (int r = 0; r < 16; ++r) o[qs][d][r] = 0.f;
    float ts[2] = {0.f, 0.f};

    // K frags for tile 0
    bf16x8 kf[4];
    #pragma unroll
    for (int c = 0; c < 4; ++c)
        kf[c] = *(const bf16x8*)(kb + c * 512);

    for (int kt = 0; kt < NN; kt += 64) {
        int tb = (kt >> 6) * 4096;

        // ---- V frags: issue early, consumed after QK+softmax ----
        bf16x8 vfr[2][2];
        #pragma unroll
        for (int kc = 0; kc < 2; ++kc)
            #pragma unroll
            for (int d = 0; d < 2; ++d)
                vfr[kc][d] = *(const bf16x8*)(vb + tb + kc * 1024 + d * 512);

        // ---- S^T per q-set: D[key_local][q] ----
        f32x16 sa[2];
        #pragma unroll
        for (int qs = 0; qs < 2; ++qs) {
            #pragma unroll
            for (int r = 0; r < 16; ++r) sa[qs][r] = 0.f;
            #pragma unroll
            for (int c = 0; c < 4; ++c)
                sa[qs] = __builtin_amdgcn_mfma_f32_32x32x16_bf16(kf[c], qf[qs][c], sa[qs], 0, 0, 0);
        }

        // ---- K frags for next tile (kf consumed above; regs reuse) ----
        if (kt + 64 < NN) {
            #pragma unroll
            for (int c = 0; c < 4; ++c)
                kf[c] = *(const bf16x8*)(kb + tb + 4096 + c * 512);
        }

        // ---- p = exp2(s), row-sum in VALU, pack to bf16 pairs ----
        unsigned dw[2][4][2];
        #pragma unroll
        for (int qs = 0; qs < 2; ++qs) {
            float t0 = 0.f;
            #pragma unroll
            for (int m4 = 0; m4 < 4; ++m4) {
                float p0 = __builtin_amdgcn_exp2f(sa[qs][m4 * 4 + 0]);
                float p1 = __builtin_amdgcn_exp2f(sa[qs][m4 * 4 + 1]);
                float p2 = __builtin_amdgcn_exp2f(sa[qs][m4 * 4 + 2]);
                float p3 = __builtin_amdgcn_exp2f(sa[qs][m4 * 4 + 3]);
                t0 += (p0 + p1) + (p2 + p3);
                dw[qs][m4][0] = pkbf(p0, p1);
                dw[qs][m4][1] = pkbf(p2, p3);
            }
            ts[qs] += t0;
        }

        // ---- PV MFMAs from register V frags ----
        #pragma unroll
        for (int kc = 0; kc < 2; ++kc) {
            #pragma unroll
            for (int qs = 0; qs < 2; ++qs) {
                int mlo = kc * 2;
                unsigned a0 = dw[qs][mlo][0],     a1 = dw[qs][mlo][1];
                unsigned b0 = dw[qs][mlo + 1][0], b1 = dw[qs][mlo + 1][1];
                union { unsigned u[4]; bf16x8 v; } pu;
#if HAVE_PLSWAP
                u32x2 r0 = __builtin_amdgcn_permlane32_swap(a0, b0, false, false);
                u32x2 r1 = __builtin_amdgcn_permlane32_swap(a1, b1, false, false);
                pu.u[0] = r0.x; pu.u[1] = r1.x; pu.u[2] = r0.y; pu.u[3] = r1.y;
#else
                unsigned own0 = hi ? b0 : a0, own1 = hi ? b1 : a1;
                unsigned snd0 = hi ? a0 : b0, snd1 = hi ? a1 : b1;
                unsigned rcv0 = __shfl_xor(snd0, 32, 64);
                unsigned rcv1 = __shfl_xor(snd1, 32, 64);
                pu.u[0] = hi ? rcv0 : own0;
                pu.u[1] = hi ? rcv1 : own1;
                pu.u[2] = hi ? own0 : rcv0;
                pu.u[3] = hi ? own1 : rcv1;
#endif
                #pragma unroll
                for (int d = 0; d < 2; ++d)
                    o[qs][d] = __builtin_amdgcn_mfma_f32_32x32x16_bf16(vfr[kc][d], pu.v, o[qs][d], 0, 0, 0);
            }
        }
    }

    // ---- epilogue: cross-kh reduction through LDS ----
    // O buffer: [q_l 128][16 chunks of 16B], chunk XOR-swizzled by (q_l & 15)
    float* Osm = (float*)smem;
    float* Ls  = (float*)(smem + 32768);
    float tsq[2];
    #pragma unroll
    for (int qs = 0; qs < 2; ++qs)
        tsq[qs] = ts[qs] + __shfl_xor(ts[qs], 32, 64);

    if (kh == 0) {
        #pragma unroll
        for (int qs = 0; qs < 2; ++qs) {
            int q_l = qh * 64 + qs * 32 + l32;
            #pragma unroll
            for (int d = 0; d < 2; ++d)
                #pragma unroll
                for (int m4 = 0; m4 < 4; ++m4) {
                    int ci = d * 8 + m4 * 2 + hi;
                    int pc = ci ^ (q_l & 15);
                    f32x4 v;
                    v[0] = o[qs][d][m4 * 4 + 0];
                    v[1] = o[qs][d][m4 * 4 + 1];
                    v[2] = o[qs][d][m4 * 4 + 2];
                    v[3] = o[qs][d][m4 * 4 + 3];
                    *(f32x4*)(Osm + q_l * 64 + pc * 4) = v;
                }
            if (!hi) Ls[q_l] = tsq[qs];
        }
    }
    __syncthreads();
    if (kh == 1) {
        #pragma unroll
        for (int qs = 0; qs < 2; ++qs) {
            int q_l = qh * 64 + qs * 32 + l32;
            #pragma unroll
            for (int d = 0; d < 2; ++d)
                #pragma unroll
                for (int m4 = 0; m4 < 4; ++m4) {
                    int ci = d * 8 + m4 * 2 + hi;
                    int pc = ci ^ (q_l & 15);
                    f32x4 v = *(const f32x4*)(Osm + q_l * 64 + pc * 4);
                    v[0] += o[qs][d][m4 * 4 + 0];
                    v[1] += o[qs][d][m4 * 4 + 1];
                    v[2] += o[qs][d][m4 * 4 + 2];
                    v[3] += o[qs][d][m4 * 4 + 3];
                    *(f32x4*)(Osm + q_l * 64 + pc * 4) = v;
                }
            if (!hi) Ls[q_l] += tsq[qs];
        }
    }
    __syncthreads();
    // ---- normalize + fully-coalesced store: 2048 x 16B chunks ----
    float* outb = out + ((size_t)hb * NN + q0) * DHH;
    #pragma unroll
    for (int i = 0; i < 8; ++i) {
        int g = tid + 256 * i;
        int q_l = g >> 4, ci = g & 15;
        int pc = ci ^ (q_l & 15);
        float inv = 1.0f / Ls[q_l];
        f32x4 v = *(const f32x4*)(Osm + q_l * 64 + pc * 4);
        v *= inv;
        *(f32x4*)(outb + g * 4) = v;
    }
}

extern "C" void kernel_launch(void* const* d_in, const int* in_sizes, int n_in,
                              void* d_out, int out_size, void* d_ws, size_t ws_size,
                              hipStream_t stream) {
    const float* data = (const float*)d_in[0];
    const float* Wq   = (const float*)d_in[1];
    const float* bq   = (const float*)d_in[2];
    const float* Wk   = (const float*)d_in[3];
    const float* bk   = (const float*)d_in[4];
    const float* Wv   = (const float*)d_in[5];
    const float* bv   = (const float*)d_in[6];
    float* out = (float*)d_out;

    char* ws = (char*)d_ws;
    bf16* xb = (bf16*)ws; ws += (size_t)8192 * 1024 * 2;       // 16 MB
    bf16* Bw = (bf16*)ws; ws += (size_t)3072 * 1024 * 2;       // 6 MB
    bf16* Qs = (bf16*)ws; ws += (size_t)HB * NN * DHH * 2;     // 16 MB
    bf16* Kf = (bf16*)ws; ws += (size_t)HB * NN * DHH * 2;     // 16 MB
    bf16* Vf = (bf16*)ws; ws += (size_t)HB * NN * DHH * 2;     // 16 MB

    pe_wtrans_kernel<<<11264, 256, 0, stream>>>(data, Wq, Wk, Wv, xb, Bw);
    gemm_qkv_fused<<<1536, 256, 0, stream>>>(xb, Bw, bq, bk, bv, Qs, Kf, Vf);
    attn_kernel<<<1024, 256, 0, stream>>>(Qs, Kf, Vf, out);
}